// Round 1
// baseline (775.722 us; speedup 1.0000x reference)
//
#include <hip/hip_runtime.h>

#define HID 128

// ---------------- CSR build ----------------

__global__ __launch_bounds__(256) void k_count(const int* __restrict__ ei, int E,
                                               int* __restrict__ deg) {
    int e = blockIdx.x * 256 + threadIdx.x;
    if (e < E) atomicAdd(&deg[ei[E + e]], 1);   // row 1 of edge_index = dst
}

__global__ __launch_bounds__(256) void k_scan1(const int* __restrict__ deg,
                                               int* __restrict__ rowptr,
                                               int* __restrict__ partial, int n) {
    __shared__ int s[256];
    int tid = threadIdx.x;
    int i = blockIdx.x * 256 + tid;
    int v = (i < n) ? deg[i] : 0;
    s[tid] = v;
    __syncthreads();
    for (int off = 1; off < 256; off <<= 1) {
        int t = (tid >= off) ? s[tid - off] : 0;
        __syncthreads();
        s[tid] += t;
        __syncthreads();
    }
    if (i < n) rowptr[i] = s[tid] - v;           // block-local exclusive
    if (tid == 255) partial[blockIdx.x] = s[255];
}

__global__ __launch_bounds__(256) void k_scan2(int* __restrict__ partial, int nb) {
    __shared__ int s[256];
    int tid = threadIdx.x;
    int v = (tid < nb) ? partial[tid] : 0;
    s[tid] = v;
    __syncthreads();
    for (int off = 1; off < 256; off <<= 1) {
        int t = (tid >= off) ? s[tid - off] : 0;
        __syncthreads();
        s[tid] += t;
        __syncthreads();
    }
    if (tid < nb) partial[tid] = s[tid] - v;     // exclusive over block sums
}

__global__ __launch_bounds__(256) void k_scan3(int* __restrict__ rowptr,
                                               const int* __restrict__ partial,
                                               int n, int E) {
    int i = blockIdx.x * 256 + threadIdx.x;
    if (i < n) rowptr[i] += partial[blockIdx.x];
    if (i == 0) rowptr[n] = E;
}

__global__ __launch_bounds__(256) void k_dis(const int* __restrict__ deg,
                                             float* __restrict__ dis, int n) {
    int i = blockIdx.x * 256 + threadIdx.x;
    if (i < n) dis[i] = 1.0f / sqrtf((float)(deg[i] + 1));  // +1 self-loop; always > 0
}

__global__ __launch_bounds__(256) void k_fill(const int* __restrict__ ei, int E,
                                              const int* __restrict__ rowptr,
                                              int* __restrict__ cursor,
                                              int* __restrict__ col) {
    int e = blockIdx.x * 256 + threadIdx.x;
    if (e < E) {
        int d = ei[E + e];
        int p = atomicAdd(&cursor[d], 1);
        col[rowptr[d] + p] = ei[e];
    }
}

// ---------------- per-layer kernels ----------------

// T[i,:] = dis[i] * (A[i,:] @ W)   (A: n x 128, W: 128 x 128 row-major)
// block: 256 threads; tile: 64 rows x 128 cols; thread: 8 rows x 4 cols.
__global__ __launch_bounds__(256) void k_gemm(const float* __restrict__ A,
                                              const float* __restrict__ W,
                                              const float* __restrict__ dis,
                                              float* __restrict__ T, int n) {
    __shared__ float As[64 * HID];   // 32 KiB
    int r0 = blockIdx.x * 64;
    int tid = threadIdx.x;
    int rows = n - r0; if (rows > 64) rows = 64;
    {
        const float4* A4 = (const float4*)(A + (size_t)r0 * HID);
        float4* S4 = (float4*)As;
        int tot = rows * (HID / 4);
        for (int i = tid; i < tot; i += 256) S4[i] = A4[i];
    }
    __syncthreads();

    int tx = tid & 31, ty = tid >> 5;
    int c0 = tx * 4, rr0 = ty * 8;

    float acc[8][4];
    #pragma unroll
    for (int r = 0; r < 8; ++r) { acc[r][0] = 0.f; acc[r][1] = 0.f; acc[r][2] = 0.f; acc[r][3] = 0.f; }

    for (int k = 0; k < HID; k += 4) {
        float4 w0 = *(const float4*)&W[(k + 0) * HID + c0];
        float4 w1 = *(const float4*)&W[(k + 1) * HID + c0];
        float4 w2 = *(const float4*)&W[(k + 2) * HID + c0];
        float4 w3 = *(const float4*)&W[(k + 3) * HID + c0];
        #pragma unroll
        for (int r = 0; r < 8; ++r) {
            float4 a = *(const float4*)&As[(rr0 + r) * HID + k];
            acc[r][0] = fmaf(a.x, w0.x, acc[r][0]);
            acc[r][0] = fmaf(a.y, w1.x, acc[r][0]);
            acc[r][0] = fmaf(a.z, w2.x, acc[r][0]);
            acc[r][0] = fmaf(a.w, w3.x, acc[r][0]);
            acc[r][1] = fmaf(a.x, w0.y, acc[r][1]);
            acc[r][1] = fmaf(a.y, w1.y, acc[r][1]);
            acc[r][1] = fmaf(a.z, w2.y, acc[r][1]);
            acc[r][1] = fmaf(a.w, w3.y, acc[r][1]);
            acc[r][2] = fmaf(a.x, w0.z, acc[r][2]);
            acc[r][2] = fmaf(a.y, w1.z, acc[r][2]);
            acc[r][2] = fmaf(a.z, w2.z, acc[r][2]);
            acc[r][2] = fmaf(a.w, w3.z, acc[r][2]);
            acc[r][3] = fmaf(a.x, w0.w, acc[r][3]);
            acc[r][3] = fmaf(a.y, w1.w, acc[r][3]);
            acc[r][3] = fmaf(a.z, w2.w, acc[r][3]);
            acc[r][3] = fmaf(a.w, w3.w, acc[r][3]);
        }
    }

    #pragma unroll
    for (int r = 0; r < 8; ++r) {
        int row = rr0 + r;
        if (row < rows) {
            float d = dis[r0 + row];
            float4 o = make_float4(acc[r][0] * d, acc[r][1] * d, acc[r][2] * d, acc[r][3] * d);
            *(float4*)&T[(size_t)(r0 + row) * HID + c0] = o;
        }
    }
}

// H[i,:] = relu(dis[i] * (T[i,:] + sum_{j in adj(i)} T[j,:]) + b)
// one wave per node, lane covers 2 features (float2).
__global__ __launch_bounds__(256) void k_agg(const float* __restrict__ T,
                                             const int* __restrict__ rowptr,
                                             const int* __restrict__ col,
                                             const float* __restrict__ dis,
                                             const float* __restrict__ b,
                                             float* __restrict__ H, int n) {
    int gw = (blockIdx.x * 256 + threadIdx.x) >> 6;
    int lane = threadIdx.x & 63;
    if (gw >= n) return;
    size_t base = (size_t)gw * HID + lane * 2;
    float2 acc = *(const float2*)&T[base];          // self-loop term (pre-scaled by dis)
    int e0 = rowptr[gw], e1 = rowptr[gw + 1];
    for (int e = e0; e < e1; ++e) {
        int j = col[e];
        float2 v = *(const float2*)&T[(size_t)j * HID + lane * 2];
        acc.x += v.x; acc.y += v.y;
    }
    float d = dis[gw];
    float2 bb = *(const float2*)&b[lane * 2];
    float2 o;
    o.x = fmaxf(fmaf(d, acc.x, bb.x), 0.0f);
    o.y = fmaxf(fmaf(d, acc.y, bb.y), 0.0f);
    *(float2*)&H[base] = o;
}

// out[i] = H[i,:] @ lin_w + lin_b    one wave per node
__global__ __launch_bounds__(256) void k_final(const float* __restrict__ H,
                                               const float* __restrict__ w,
                                               const float* __restrict__ lb,
                                               float* __restrict__ out, int n) {
    int gw = (blockIdx.x * 256 + threadIdx.x) >> 6;
    int lane = threadIdx.x & 63;
    if (gw >= n) return;
    float2 h = *(const float2*)&H[(size_t)gw * HID + lane * 2];
    float2 ww = *(const float2*)&w[lane * 2];
    float s = h.x * ww.x + h.y * ww.y;
    #pragma unroll
    for (int o = 32; o > 0; o >>= 1) s += __shfl_down(s, o, 64);
    if (lane == 0) out[gw] = s + lb[0];
}

// ---------------- launch ----------------

extern "C" void kernel_launch(void* const* d_in, const int* in_sizes, int n_in,
                              void* d_out, int out_size, void* d_ws, size_t ws_size,
                              hipStream_t stream) {
    const float* x     = (const float*)d_in[0];
    const int*   ei    = (const int*)d_in[1];
    const float* Ws    = (const float*)d_in[2];
    const float* bs    = (const float*)d_in[3];
    const float* lin_w = (const float*)d_in[4];
    const float* lin_b = (const float*)d_in[5];
    float* out = (float*)d_out;

    int n = in_sizes[0] / HID;           // 50000
    int E = in_sizes[1] / 2;             // 600000
    int L = in_sizes[2] / (HID * HID);   // 7

    char* ws = (char*)d_ws;
    size_t off = 0;
    auto alloc = [&](size_t bytes) -> void* {
        void* p = ws + off;
        off += (bytes + 255) & ~(size_t)255;
        return p;
    };
    int*   deg     = (int*)alloc((size_t)n * 4);
    int*   cursor  = (int*)alloc((size_t)n * 4);
    int*   rowptr  = (int*)alloc((size_t)(n + 1) * 4);
    int*   partial = (int*)alloc(1024);
    float* dis     = (float*)alloc((size_t)n * 4);
    int*   col     = (int*)alloc((size_t)E * 4);
    float* hbuf    = (float*)alloc((size_t)n * HID * 4);
    float* tbuf    = (float*)alloc((size_t)n * HID * 4);
    (void)ws_size;

    hipMemsetAsync(deg, 0, (size_t)n * 4, stream);
    hipMemsetAsync(cursor, 0, (size_t)n * 4, stream);

    int eb = (E + 255) / 256;
    int nb = (n + 255) / 256;   // 196 (<=256 so single-block scan2 works)
    k_count<<<eb, 256, 0, stream>>>(ei, E, deg);
    k_scan1<<<nb, 256, 0, stream>>>(deg, rowptr, partial, n);
    k_scan2<<<1, 256, 0, stream>>>(partial, nb);
    k_scan3<<<nb, 256, 0, stream>>>(rowptr, partial, n, E);
    k_dis<<<nb, 256, 0, stream>>>(deg, dis, n);
    k_fill<<<eb, 256, 0, stream>>>(ei, E, rowptr, cursor, col);

    const float* hin = x;
    int gb = (n + 63) / 64;      // GEMM blocks
    int wb = (n + 3) / 4;        // 4 waves(=nodes) per 256-thread block
    for (int l = 0; l < L; ++l) {
        k_gemm<<<gb, 256, 0, stream>>>(hin, Ws + (size_t)l * HID * HID, dis, tbuf, n);
        k_agg<<<wb, 256, 0, stream>>>(tbuf, rowptr, col, dis, bs + (size_t)l * HID, hbuf, n);
        hin = hbuf;
    }
    k_final<<<wb, 256, 0, stream>>>(hbuf, lin_w, lin_b, out, n);
}

// Round 2
// 678.301 us; speedup vs baseline: 1.1436x; 1.1436x over previous
//
#include <hip/hip_runtime.h>

#define HID 128
#define ASPITCH 132   // 128 + 4 pad: keeps 16B alignment, breaks power-of-2 bank stride

// ---------------- CSR build ----------------

__global__ __launch_bounds__(256) void k_count(const int* __restrict__ ei, int E,
                                               int* __restrict__ deg) {
    int e = blockIdx.x * 256 + threadIdx.x;
    if (e < E) atomicAdd(&deg[ei[E + e]], 1);   // row 1 of edge_index = dst
}

__global__ __launch_bounds__(256) void k_scan1(const int* __restrict__ deg,
                                               int* __restrict__ rowptr,
                                               int* __restrict__ partial, int n) {
    __shared__ int s[256];
    int tid = threadIdx.x;
    int i = blockIdx.x * 256 + tid;
    int v = (i < n) ? deg[i] : 0;
    s[tid] = v;
    __syncthreads();
    for (int off = 1; off < 256; off <<= 1) {
        int t = (tid >= off) ? s[tid - off] : 0;
        __syncthreads();
        s[tid] += t;
        __syncthreads();
    }
    if (i < n) rowptr[i] = s[tid] - v;           // block-local exclusive
    if (tid == 255) partial[blockIdx.x] = s[255];
}

__global__ __launch_bounds__(256) void k_scan2(int* __restrict__ partial, int nb) {
    __shared__ int s[256];
    int tid = threadIdx.x;
    int v = (tid < nb) ? partial[tid] : 0;
    s[tid] = v;
    __syncthreads();
    for (int off = 1; off < 256; off <<= 1) {
        int t = (tid >= off) ? s[tid - off] : 0;
        __syncthreads();
        s[tid] += t;
        __syncthreads();
    }
    if (tid < nb) partial[tid] = s[tid] - v;     // exclusive over block sums
}

__global__ __launch_bounds__(256) void k_scan3(int* __restrict__ rowptr,
                                               const int* __restrict__ partial,
                                               int n, int E) {
    int i = blockIdx.x * 256 + threadIdx.x;
    if (i < n) rowptr[i] += partial[blockIdx.x];
    if (i == 0) rowptr[n] = E;
}

__global__ __launch_bounds__(256) void k_dis(const int* __restrict__ deg,
                                             float* __restrict__ dis, int n) {
    int i = blockIdx.x * 256 + threadIdx.x;
    if (i < n) dis[i] = 1.0f / sqrtf((float)(deg[i] + 1));  // +1 self-loop
}

__global__ __launch_bounds__(256) void k_fill(const int* __restrict__ ei, int E,
                                              const int* __restrict__ rowptr,
                                              int* __restrict__ cursor,
                                              int* __restrict__ col) {
    int e = blockIdx.x * 256 + threadIdx.x;
    if (e < E) {
        int d = ei[E + e];
        int p = atomicAdd(&cursor[d], 1);
        col[rowptr[d] + p] = ei[e];
    }
}

// ---------------- per-layer kernels ----------------

// T[i,:] = dis[i] * (A[i,:] @ W)
// block: 256 threads; tile 64 rows x 128 cols; thread: 4 rows x 8 cols.
// LDS b128 per wave per K-loop = 128 (vs 4096 FMA) -> FMA-bound, not LDS-bound.
__global__ __launch_bounds__(256) void k_gemm(const float* __restrict__ A,
                                              const float* __restrict__ W,
                                              const float* __restrict__ dis,
                                              float* __restrict__ T, int n) {
    __shared__ float As[64 * ASPITCH];   // ~33 KiB
    int r0 = blockIdx.x * 64;
    int tid = threadIdx.x;
    int rows = n - r0; if (rows > 64) rows = 64;
    {
        const float4* A4 = (const float4*)(A + (size_t)r0 * HID);
        int tot = rows * (HID / 4);
        for (int i = tid; i < tot; i += 256) {
            int row = i >> 5, c = (i & 31) << 2;
            *(float4*)&As[row * ASPITCH + c] = A4[i];
        }
    }
    __syncthreads();

    int tx = tid & 15, ty = tid >> 4;        // 16 col-groups x 16 row-groups
    int c0 = tx * 8, rr0 = ty * 4;

    float acc[4][8];
    #pragma unroll
    for (int r = 0; r < 4; ++r)
        #pragma unroll
        for (int c = 0; c < 8; ++c) acc[r][c] = 0.0f;

    for (int k = 0; k < HID; k += 4) {
        float wf[4][8];
        #pragma unroll
        for (int i = 0; i < 4; ++i) {
            float4 w0 = *(const float4*)&W[(k + i) * HID + c0];
            float4 w1 = *(const float4*)&W[(k + i) * HID + c0 + 4];
            wf[i][0] = w0.x; wf[i][1] = w0.y; wf[i][2] = w0.z; wf[i][3] = w0.w;
            wf[i][4] = w1.x; wf[i][5] = w1.y; wf[i][6] = w1.z; wf[i][7] = w1.w;
        }
        #pragma unroll
        for (int r = 0; r < 4; ++r) {
            float4 a = *(const float4*)&As[(rr0 + r) * ASPITCH + k];
            #pragma unroll
            for (int c = 0; c < 8; ++c) {
                float t = acc[r][c];
                t = fmaf(a.x, wf[0][c], t);
                t = fmaf(a.y, wf[1][c], t);
                t = fmaf(a.z, wf[2][c], t);
                t = fmaf(a.w, wf[3][c], t);
                acc[r][c] = t;
            }
        }
    }

    #pragma unroll
    for (int r = 0; r < 4; ++r) {
        int row = rr0 + r;
        if (row < rows) {
            float d = dis[r0 + row];
            float4 o0 = make_float4(acc[r][0] * d, acc[r][1] * d, acc[r][2] * d, acc[r][3] * d);
            float4 o1 = make_float4(acc[r][4] * d, acc[r][5] * d, acc[r][6] * d, acc[r][7] * d);
            *(float4*)&T[(size_t)(r0 + row) * HID + c0] = o0;
            *(float4*)&T[(size_t)(r0 + row) * HID + c0 + 4] = o1;
        }
    }
}

// H[i,:] = relu(dis[i] * (T[i,:] + sum_{j in adj(i)} T[j,:]) + b)
// half-wave (32 lanes x float4) per node; edge loop unrolled x4 for MLP.
__global__ __launch_bounds__(256) void k_agg(const float* __restrict__ T,
                                             const int* __restrict__ rowptr,
                                             const int* __restrict__ col,
                                             const float* __restrict__ dis,
                                             const float* __restrict__ b,
                                             float* __restrict__ H, int n) {
    int node = (blockIdx.x * 256 + threadIdx.x) >> 5;
    int lane = threadIdx.x & 31;
    if (node >= n) return;
    size_t base = (size_t)node * HID + lane * 4;
    float4 acc = *(const float4*)&T[base];          // self-loop (pre-scaled by dis[j])
    int e = rowptr[node], e1 = rowptr[node + 1];
    for (; e + 4 <= e1; e += 4) {
        int j0 = col[e + 0];
        int j1 = col[e + 1];
        int j2 = col[e + 2];
        int j3 = col[e + 3];
        float4 v0 = *(const float4*)&T[(size_t)j0 * HID + lane * 4];
        float4 v1 = *(const float4*)&T[(size_t)j1 * HID + lane * 4];
        float4 v2 = *(const float4*)&T[(size_t)j2 * HID + lane * 4];
        float4 v3 = *(const float4*)&T[(size_t)j3 * HID + lane * 4];
        acc.x += (v0.x + v1.x) + (v2.x + v3.x);
        acc.y += (v0.y + v1.y) + (v2.y + v3.y);
        acc.z += (v0.z + v1.z) + (v2.z + v3.z);
        acc.w += (v0.w + v1.w) + (v2.w + v3.w);
    }
    for (; e < e1; ++e) {
        int j = col[e];
        float4 v = *(const float4*)&T[(size_t)j * HID + lane * 4];
        acc.x += v.x; acc.y += v.y; acc.z += v.z; acc.w += v.w;
    }
    float d = dis[node];
    float4 bb = *(const float4*)&b[lane * 4];
    float4 o;
    o.x = fmaxf(fmaf(d, acc.x, bb.x), 0.0f);
    o.y = fmaxf(fmaf(d, acc.y, bb.y), 0.0f);
    o.z = fmaxf(fmaf(d, acc.z, bb.z), 0.0f);
    o.w = fmaxf(fmaf(d, acc.w, bb.w), 0.0f);
    *(float4*)&H[base] = o;
}

// out[i] = H[i,:] @ lin_w + lin_b    half-wave per node
__global__ __launch_bounds__(256) void k_final(const float* __restrict__ H,
                                               const float* __restrict__ w,
                                               const float* __restrict__ lb,
                                               float* __restrict__ out, int n) {
    int node = (blockIdx.x * 256 + threadIdx.x) >> 5;
    int lane = threadIdx.x & 31;
    if (node >= n) return;
    float4 h = *(const float4*)&H[(size_t)node * HID + lane * 4];
    float4 ww = *(const float4*)&w[lane * 4];
    float s = h.x * ww.x + h.y * ww.y + h.z * ww.z + h.w * ww.w;
    #pragma unroll
    for (int o = 16; o > 0; o >>= 1) s += __shfl_down(s, o, 64);  // stays within half
    if (lane == 0) out[node] = s + lb[0];
}

// ---------------- launch ----------------

extern "C" void kernel_launch(void* const* d_in, const int* in_sizes, int n_in,
                              void* d_out, int out_size, void* d_ws, size_t ws_size,
                              hipStream_t stream) {
    const float* x     = (const float*)d_in[0];
    const int*   ei    = (const int*)d_in[1];
    const float* Ws    = (const float*)d_in[2];
    const float* bs    = (const float*)d_in[3];
    const float* lin_w = (const float*)d_in[4];
    const float* lin_b = (const float*)d_in[5];
    float* out = (float*)d_out;

    int n = in_sizes[0] / HID;           // 50000
    int E = in_sizes[1] / 2;             // 600000
    int L = in_sizes[2] / (HID * HID);   // 7

    char* ws = (char*)d_ws;
    size_t off = 0;
    auto alloc = [&](size_t bytes) -> void* {
        void* p = ws + off;
        off += (bytes + 255) & ~(size_t)255;
        return p;
    };
    int*   deg     = (int*)alloc((size_t)n * 4);
    int*   cursor  = (int*)alloc((size_t)n * 4);
    int*   rowptr  = (int*)alloc((size_t)(n + 1) * 4);
    int*   partial = (int*)alloc(1024);
    float* dis     = (float*)alloc((size_t)n * 4);
    int*   col     = (int*)alloc((size_t)E * 4);
    float* hbuf    = (float*)alloc((size_t)n * HID * 4);
    float* tbuf    = (float*)alloc((size_t)n * HID * 4);
    (void)ws_size;

    hipMemsetAsync(deg, 0, (size_t)n * 4, stream);
    hipMemsetAsync(cursor, 0, (size_t)n * 4, stream);

    int eb = (E + 255) / 256;
    int nb = (n + 255) / 256;
    k_count<<<eb, 256, 0, stream>>>(ei, E, deg);
    k_scan1<<<nb, 256, 0, stream>>>(deg, rowptr, partial, n);
    k_scan2<<<1, 256, 0, stream>>>(partial, nb);
    k_scan3<<<nb, 256, 0, stream>>>(rowptr, partial, n, E);
    k_dis<<<nb, 256, 0, stream>>>(deg, dis, n);
    k_fill<<<eb, 256, 0, stream>>>(ei, E, rowptr, cursor, col);

    const float* hin = x;
    int gb = (n + 63) / 64;      // GEMM blocks
    int hb = (n + 7) / 8;        // 8 half-waves (=nodes) per 256-thread block
    for (int l = 0; l < L; ++l) {
        k_gemm<<<gb, 256, 0, stream>>>(hin, Ws + (size_t)l * HID * HID, dis, tbuf, n);
        k_agg<<<hb, 256, 0, stream>>>(tbuf, rowptr, col, dis, bs + (size_t)l * HID, hbuf, n);
        hin = hbuf;
    }
    k_final<<<hb, 256, 0, stream>>>(hbuf, lin_w, lin_b, out, n);
}